// Round 8
// baseline (190.691 us; speedup 1.0000x reference)
//
#include <hip/hip_runtime.h>

#define NN 4096
#define BB 512

typedef __attribute__((ext_vector_type(4))) float f32x4;    // MFMA C/D frag
typedef __attribute__((ext_vector_type(2))) long long2v;    // 16B LDS read
typedef unsigned short ushort;
typedef unsigned char uchar;
typedef unsigned int uint;
typedef __attribute__((ext_vector_type(4))) ushort ushort4v;

#define ASCALE 16384.0f            // 2^14 scale for a -> fp8
#define AINV   6.103515625e-05f    // 2^-14

__device__ __forceinline__ float scal_val(const void* p) {
    int b = *(const int*)p;
    if (b >= 1 && b <= 1000000) return (float)b;
    return __int_as_float(b);
}

// f32 -> bf16 bits (RNE) and back
__device__ __forceinline__ ushort f2bf(float x) {
    unsigned u = __float_as_uint(x);
    u += 0x7fffu + ((u >> 16) & 1u);
    return (ushort)(u >> 16);
}
__device__ __forceinline__ float bf2f(ushort b) {
    return __uint_as_float((uint)b << 16);
}

// pack 4 floats -> 4 fp8 e4m3 bytes (OCP, RNE+sat via v_cvt_pk_fp8_f32)
__device__ __forceinline__ uint pack4_fp8(float a, float b, float c, float d) {
    int v = __builtin_amdgcn_cvt_pk_fp8_f32(a, b, 0, false);
    v = __builtin_amdgcn_cvt_pk_fp8_f32(c, d, v, true);
    return (uint)v;
}

__device__ __forceinline__ void gload16(const void* g, void* l) {
    __builtin_amdgcn_global_load_lds(
        (const __attribute__((address_space(1))) unsigned int*)g,
        (__attribute__((address_space(3))) unsigned int*)l, 16, 0, 0);
}

__device__ __forceinline__ double wave_sum(double v) {
#pragma unroll
    for (int s = 32; s > 0; s >>= 1) v += __shfl_down(v, s, 64);
    return v;
}

// k-permutation within each 64-byte k-group: orig chunk c=k>>3 (ks=c>>2,
// quad=c&3) stored at pos quad*16 + ks*8 + (k&7).  One b128 at unit `quad`
// yields ks0 in bytes[0:8) and ks1 in bytes[8:16).
__device__ __forceinline__ int kperm(int kk) {   // kk in [0,64), mult of 4
    int c = kk >> 3;
    return (c & 3) * 16 + (c >> 2) * 8 + (kk & 7);
}

// Partials (doubles): [0,1024) t1 | [1024,2048) kl | [2048,2560) t2
// | [2560,3072) t3.  Ticket counter (uint) at byte offset 24576.

// ---------------------------------------------------------------------------
// Merged prep. Blocks [0,4096): K -> Kb (fp8, k-permuted) + KTb (fp8,
// transposed, k-permuted).  Blocks [4096,4608): U -> fT (fp8 [j][k] permuted).
// ---------------------------------------------------------------------------
__global__ __launch_bounds__(256) void k_prep(const float* __restrict__ K,
                                              const float* __restrict__ U,
                                              uchar* __restrict__ Kb,
                                              uchar* __restrict__ KTb,
                                              uchar* __restrict__ fT,
                                              const void* epsp, const void* lamp) {
    __shared__ float tile[64][65];
    const int t = threadIdx.x;
    const int tx = t & 15, ty = t >> 4;
    const int bid = blockIdx.x;
    const int pp = kperm(tx * 4);

    if (bid < 4096) {
        const int c0 = (bid & 63) * 64, r0 = (bid >> 6) * 64;
#pragma unroll
        for (int it = 0; it < 4; ++it) {
            int row = ty + it * 16;
            float4 v = *(const float4*)&K[(size_t)(r0 + row) * NN + c0 + tx * 4];
            *(uint*)&Kb[(size_t)(r0 + row) * NN + c0 + pp] =
                pack4_fp8(v.x, v.y, v.z, v.w);
            tile[row][tx * 4 + 0] = v.x;
            tile[row][tx * 4 + 1] = v.y;
            tile[row][tx * 4 + 2] = v.z;
            tile[row][tx * 4 + 3] = v.w;
        }
        __syncthreads();
#pragma unroll
        for (int it = 0; it < 4; ++it) {
            int row = ty + it * 16;  // col within tile -> KT row (c0+row)
            *(uint*)&KTb[(size_t)(c0 + row) * NN + r0 + pp] =
                pack4_fp8(tile[tx * 4 + 0][row], tile[tx * 4 + 1][row],
                          tile[tx * 4 + 2][row], tile[tx * 4 + 3][row]);
        }
    } else {
        const int r = bid - 4096;
        const int c0 = (r & 7) * 64;   // U col tile (j)
        const int r0 = (r >> 3) * 64;  // U row tile (k)
        const float eps = scal_val(epsp), lam = scal_val(lamp);
        const float rr = lam / eps;
#pragma unroll
        for (int it = 0; it < 4; ++it) {
            int row = ty + it * 16;
            float4 v = *(const float4*)&U[(size_t)(r0 + row) * BB + c0 + tx * 4];
            float uu[4] = {v.x, v.y, v.z, v.w};
#pragma unroll
            for (int k = 0; k < 4; ++k) {
                float L = __logf(lam / (lam - uu[k]));
                tile[row][tx * 4 + k] = __expf(rr * L);
            }
        }
        __syncthreads();
#pragma unroll
        for (int it = 0; it < 4; ++it) {
            int row = ty + it * 16;
            *(uint*)&fT[(size_t)(c0 + row) * NN + r0 + pp] =
                pack4_fp8(tile[tx * 4 + 0][row], tile[tx * 4 + 1][row],
                          tile[tx * 4 + 2][row], tile[tx * 4 + 3][row]);
        }
    }
}

// ---------------------------------------------------------------------------
// GEMM1 (fp8 MFMA, K-split 4): partial Y1 = Kb@f over K-quarter, stored bf16.
// Tile 128(M)x64(j), BK=64, dbuf, permuted-b128 LDS.  Grid 1024 (4/CU).
// ---------------------------------------------------------------------------
__global__ __launch_bounds__(256) void k_gemm1(const uchar* __restrict__ Kb,
                                               const uchar* __restrict__ fT,
                                               ushort* __restrict__ Y1b) {
    __shared__ __align__(16) uchar As[2][128 * 64];   // 16 KB
    __shared__ __align__(16) uchar Bf[2][64 * 64];    //  8 KB

    const int tid = threadIdx.x;
    const int lane = tid & 63;
    const int w = tid >> 6;
    const int wm = w & 1, wn = w >> 1;
    const int bid = blockIdx.x;
    const int kh = bid & 3;                  // K-quarter
    const int i0 = ((bid >> 2) & 31) * 128;  // M panel
    const int j0 = (bid >> 7) * 64;          // j panel
    const int quad = lane >> 4;
    const int l15 = lane & 15;
    const int sw = (l15 >> 1) & 3;           // read-side unit swizzle key

    f32x4 zero = {0.f, 0.f, 0.f, 0.f};
    f32x4 acc[4][2];
#pragma unroll
    for (int mt = 0; mt < 4; ++mt)
#pragma unroll
        for (int nt = 0; nt < 2; ++nt) acc[mt][nt] = zero;

    const int rl = lane >> 2;                              // 0..15 row in slab
    const int goff = ((lane & 3) ^ ((lane >> 3) & 3)) * 16; // swizzled unit

    auto stage = [&](int k0, int b) {
#pragma unroll
        for (int it = 0; it < 2; ++it) {
            const int rbase = w * 32 + it * 16;
            gload16(Kb + (size_t)(i0 + rbase + rl) * NN + k0 + goff,
                    &As[b][rbase * 64]);
        }
        gload16(fT + (size_t)(j0 + w * 16 + rl) * NN + k0 + goff,
                &Bf[b][(w * 16) * 64]);
    };

    const int kbase = kh * (NN / 4);
    stage(kbase, 0);
    __syncthreads();
    const int uoff = ((quad ^ sw) << 4);
    for (int step = 0; step < NN / 256; ++step) {   // 16 steps of BK=64
        const int cur = step & 1;
        if (step < NN / 256 - 1) stage(kbase + (step + 1) * 64, cur ^ 1);
        long2v av[4], bv[2];
#pragma unroll
        for (int mt = 0; mt < 4; ++mt)
            av[mt] = *(const long2v*)&As[cur][(wm * 64 + mt * 16 + l15) * 64 + uoff];
#pragma unroll
        for (int nt = 0; nt < 2; ++nt)
            bv[nt] = *(const long2v*)&Bf[cur][(wn * 32 + nt * 16 + l15) * 64 + uoff];
#pragma unroll
        for (int mt = 0; mt < 4; ++mt)
#pragma unroll
            for (int nt = 0; nt < 2; ++nt) {
                acc[mt][nt] = __builtin_amdgcn_mfma_f32_16x16x32_fp8_fp8(
                    av[mt].x, bv[nt].x, acc[mt][nt], 0, 0, 0);
                acc[mt][nt] = __builtin_amdgcn_mfma_f32_16x16x32_fp8_fp8(
                    av[mt].y, bv[nt].y, acc[mt][nt], 0, 0, 0);
            }
        __syncthreads();
    }

    // Store bf16 partial [kh][i][j].  C/D layout: col=lane&15, row=quad*4+reg.
    ushort* o1 = Y1b + (size_t)kh * NN * BB;
#pragma unroll
    for (int mt = 0; mt < 4; ++mt)
#pragma unroll
        for (int nt = 0; nt < 2; ++nt) {
            const int ib = i0 + wm * 64 + mt * 16 + quad * 4;
            const int j = j0 + wn * 32 + nt * 16 + l15;
#pragma unroll
            for (int r = 0; r < 4; ++r)
                o1[(size_t)(ib + r) * BB + j] = f2bf(acc[mt][nt][r]);
        }
}

// ---------------------------------------------------------------------------
// Epilogue: Y1 = sum of 4 bf16 quarters; a = P/Y1; t2 += P*log(a), t3 += P;
// aT (fp8 * 2^14, [j][i] k-permuted) via LDS transpose.  No atomics.
// ---------------------------------------------------------------------------
__global__ __launch_bounds__(256) void k_epi(const ushort* __restrict__ Y1b,
                                             const float* __restrict__ P,
                                             uchar* __restrict__ aT,
                                             double* __restrict__ parts) {
    __shared__ float ta[64][65];
    __shared__ double bred[4][2];
    const int t = threadIdx.x;
    const int lane = t & 63;
    const int w = t >> 6;
    const int tx = t & 15, ty = t >> 4;
    const int j0 = blockIdx.x * 64;
    const int i0 = blockIdx.y * 64;
    const int bid = blockIdx.y * 8 + blockIdx.x;
    const size_t H = (size_t)NN * BB;
    const int pp = kperm(tx * 4);

    double t2 = 0.0, t3 = 0.0;
#pragma unroll
    for (int it = 0; it < 4; ++it) {
        int row = ty + it * 16;
        size_t off = (size_t)(i0 + row) * BB + j0 + tx * 4;
        ushort4v q0 = *(const ushort4v*)(Y1b + off);
        ushort4v q1 = *(const ushort4v*)(Y1b + H + off);
        ushort4v q2 = *(const ushort4v*)(Y1b + 2 * H + off);
        ushort4v q3 = *(const ushort4v*)(Y1b + 3 * H + off);
        float4 p4 = *(const float4*)(P + off);
        float pv[4] = {p4.x, p4.y, p4.z, p4.w};
#pragma unroll
        for (int e = 0; e < 4; ++e) {
            float y1 = bf2f(q0[e]) + bf2f(q1[e]) + bf2f(q2[e]) + bf2f(q3[e]);
            float aij = pv[e] / y1;
            t2 += (double)(pv[e] * __logf(aij));
            t3 += (double)pv[e];
            ta[row][tx * 4 + e] = aij * ASCALE;
        }
    }
    __syncthreads();
#pragma unroll
    for (int it = 0; it < 4; ++it) {
        int row = ty + it * 16;  // col within tile -> aT row (j0+row)
        *(uint*)&aT[(size_t)(j0 + row) * NN + i0 + pp] =
            pack4_fp8(ta[tx * 4 + 0][row], ta[tx * 4 + 1][row],
                      ta[tx * 4 + 2][row], ta[tx * 4 + 3][row]);
    }

    t2 = wave_sum(t2); t3 = wave_sum(t3);
    if (lane == 0) { bred[w][0] = t2; bred[w][1] = t3; }
    __syncthreads();
    if (t == 0) {
        double b = 0, c = 0;
#pragma unroll
        for (int ww = 0; ww < 4; ++ww) { b += bred[ww][0]; c += bred[ww][1]; }
        parts[2048 + bid] = b;
        parts[2560 + bid] = c;
    }
}

// ---------------------------------------------------------------------------
// GEMM2 (fp8 MFMA, K-split 4): partial S' = KTb @ a' (a scaled 2^14).
// Epilogue: t1 += g*S, kl -= f*(1+L)*S (both linear in S).  LAST block
// (device-scope ticket) performs the final reduction and writes out.
// ---------------------------------------------------------------------------
__global__ __launch_bounds__(256) void k_gemm2(const uchar* __restrict__ KTb,
                                               const uchar* __restrict__ aT,
                                               const float* __restrict__ U,
                                               const void* epsp, const void* lamp,
                                               double* __restrict__ parts,
                                               uint* __restrict__ ticket,
                                               float* __restrict__ out) {
    __shared__ __align__(16) uchar As[2][128 * 64];
    __shared__ __align__(16) uchar Bs[2][64 * 64];
    __shared__ double bred[4][2];
    __shared__ double red[4][4];
    __shared__ int amlast;

    const float eps = scal_val(epsp), lam = scal_val(lamp);
    const float rr = lam / eps;
    const int tid = threadIdx.x;
    const int lane = tid & 63;
    const int w = tid >> 6;
    const int wm = w & 1, wn = w >> 1;
    const int bid = blockIdx.x;
    const int kh = bid & 3;
    const int i0 = ((bid >> 2) & 31) * 128;
    const int j0 = (bid >> 7) * 64;
    const int quad = lane >> 4;
    const int l15 = lane & 15;
    const int sw = (l15 >> 1) & 3;

    f32x4 zero = {0.f, 0.f, 0.f, 0.f};
    f32x4 acc[4][2];
#pragma unroll
    for (int mt = 0; mt < 4; ++mt)
#pragma unroll
        for (int nt = 0; nt < 2; ++nt) acc[mt][nt] = zero;

    const int rl = lane >> 2;
    const int goff = ((lane & 3) ^ ((lane >> 3) & 3)) * 16;

    auto stage = [&](int k0, int b) {
#pragma unroll
        for (int it = 0; it < 2; ++it) {
            const int rbase = w * 32 + it * 16;
            gload16(KTb + (size_t)(i0 + rbase + rl) * NN + k0 + goff,
                    &As[b][rbase * 64]);
        }
        gload16(aT + (size_t)(j0 + w * 16 + rl) * NN + k0 + goff,
                &Bs[b][(w * 16) * 64]);
    };

    const int kbase = kh * (NN / 4);
    stage(kbase, 0);
    __syncthreads();
    const int uoff = ((quad ^ sw) << 4);
    for (int step = 0; step < NN / 256; ++step) {
        const int cur = step & 1;
        if (step < NN / 256 - 1) stage(kbase + (step + 1) * 64, cur ^ 1);
        long2v av[4], bv[2];
#pragma unroll
        for (int mt = 0; mt < 4; ++mt)
            av[mt] = *(const long2v*)&As[cur][(wm * 64 + mt * 16 + l15) * 64 + uoff];
#pragma unroll
        for (int nt = 0; nt < 2; ++nt)
            bv[nt] = *(const long2v*)&Bs[cur][(wn * 32 + nt * 16 + l15) * 64 + uoff];
#pragma unroll
        for (int mt = 0; mt < 4; ++mt)
#pragma unroll
            for (int nt = 0; nt < 2; ++nt) {
                acc[mt][nt] = __builtin_amdgcn_mfma_f32_16x16x32_fp8_fp8(
                    av[mt].x, bv[nt].x, acc[mt][nt], 0, 0, 0);
                acc[mt][nt] = __builtin_amdgcn_mfma_f32_16x16x32_fp8_fp8(
                    av[mt].y, bv[nt].y, acc[mt][nt], 0, 0, 0);
            }
        __syncthreads();
    }

    double t1p = 0.0, klp = 0.0;
#pragma unroll
    for (int mt = 0; mt < 4; ++mt)
#pragma unroll
        for (int nt = 0; nt < 2; ++nt) {
            const int ib = i0 + wm * 64 + mt * 16 + quad * 4;  // k index
            const int j = j0 + wn * 32 + nt * 16 + l15;
#pragma unroll
            for (int r = 0; r < 4; ++r) {
                float s = acc[mt][nt][r] * AINV;
                float u = U[(size_t)(ib + r) * BB + j];
                float L = __logf(lam / (lam - u));
                float fv = __expf(rr * L);
                t1p += (double)(fv * rr * L * s);       // g*S
                klp -= (double)(fv * (1.0f + L) * s);   // -f*(1+L)*S
            }
        }

    t1p = wave_sum(t1p); klp = wave_sum(klp);
    if (lane == 0) { bred[w][0] = t1p; bred[w][1] = klp; }
    __syncthreads();
    if (tid == 0) {
        double a = 0, b = 0;
#pragma unroll
        for (int ww = 0; ww < 4; ++ww) { a += bred[ww][0]; b += bred[ww][1]; }
        parts[bid] = a;
        parts[1024 + bid] = b;
        __threadfence();
        uint tk = atomicAdd(ticket, 1u);
        amlast = (tk == 1023u);
    }
    __syncthreads();

    if (amlast) {
        // Final reduction (atomic reads dodge per-XCD L2 staleness).
        double s0 = 0.0, s1 = 0.0, s2 = 0.0, s3 = 0.0;
        for (int i = tid; i < 1024; i += 256) {
            s0 += atomicAdd(&parts[i], 0.0);          // t1
            s1 += atomicAdd(&parts[1024 + i], 0.0);   // kl
        }
        for (int i = tid; i < 512; i += 256) {
            s2 += atomicAdd(&parts[2048 + i], 0.0);   // t2
            s3 += atomicAdd(&parts[2560 + i], 0.0);   // t3
        }
        s0 = wave_sum(s0); s1 = wave_sum(s1); s2 = wave_sum(s2); s3 = wave_sum(s3);
        if (lane == 0) { red[w][0] = s0; red[w][1] = s1; red[w][2] = s2; red[w][3] = s3; }
        __syncthreads();
        if (tid == 0) {
            double t1 = 0, kl = 0, t2 = 0, t3 = 0;
#pragma unroll
            for (int ww = 0; ww < 4; ++ww) {
                t1 += red[ww][0]; kl += red[ww][1]; t2 += red[ww][2]; t3 += red[ww][3];
            }
            out[0] = (float)((double)eps * (t1 + t2 - t3) + (double)lam * kl);
        }
    }
}

extern "C" void kernel_launch(void* const* d_in, const int* in_sizes, int n_in,
                              void* d_out, int out_size, void* d_ws, size_t ws_size,
                              hipStream_t stream) {
    const float* U = (const float*)d_in[0];
    const float* P = (const float*)d_in[1];
    const float* K = (const float*)d_in[2];
    const void* epsp = d_in[3];
    const void* lamp = d_in[4];

    // ws: parts 24KB + ticket@24576 (pad 64KB) | Kb 16M | KTb 16M | fT 2M
    //     | aT 2M | Y1b 16M (4 bf16 quarters)
    double* parts = (double*)d_ws;
    uint* ticket = (uint*)((char*)d_ws + 24576);
    char* base = (char*)d_ws + (64 << 10);
    uchar* Kb   = (uchar*)base;
    uchar* KTb  = (uchar*)(base + ((size_t)16 << 20));
    uchar* fT   = (uchar*)(base + ((size_t)32 << 20));
    uchar* aT   = (uchar*)(base + ((size_t)34 << 20));
    ushort* Y1b = (ushort*)(base + ((size_t)36 << 20));

    hipMemsetAsync(ticket, 0, sizeof(uint), stream);

    k_prep<<<4608, 256, 0, stream>>>(K, U, Kb, KTb, fT, epsp, lamp);
    k_gemm1<<<1024, 256, 0, stream>>>(Kb, fT, Y1b);
    k_epi<<<dim3(8, 64), 256, 0, stream>>>(Y1b, P, aT, parts);
    k_gemm2<<<1024, 256, 0, stream>>>(KTb, aT, U, epsp, lamp, parts, ticket,
                                      (float*)d_out);
}

// Round 9
// 169.070 us; speedup vs baseline: 1.1279x; 1.1279x over previous
//
#include <hip/hip_runtime.h>

#define NN 4096
#define BB 512

typedef __attribute__((ext_vector_type(4))) float f32x4;    // MFMA C/D frag
typedef __attribute__((ext_vector_type(2))) long long2v;    // 16B LDS read
typedef unsigned short ushort;
typedef unsigned char uchar;
typedef unsigned int uint;
typedef __attribute__((ext_vector_type(4))) ushort ushort4v;

#define ASCALE 16384.0f            // 2^14 scale for a -> fp8
#define AINV   6.103515625e-05f    // 2^-14

__device__ __forceinline__ float scal_val(const void* p) {
    int b = *(const int*)p;
    if (b >= 1 && b <= 1000000) return (float)b;
    return __int_as_float(b);
}

// f32 -> bf16 bits (RNE) and back
__device__ __forceinline__ ushort f2bf(float x) {
    unsigned u = __float_as_uint(x);
    u += 0x7fffu + ((u >> 16) & 1u);
    return (ushort)(u >> 16);
}
__device__ __forceinline__ float bf2f(ushort b) {
    return __uint_as_float((uint)b << 16);
}

// pack 4 floats -> 4 fp8 e4m3 bytes (OCP, RNE+sat via v_cvt_pk_fp8_f32)
__device__ __forceinline__ uint pack4_fp8(float a, float b, float c, float d) {
    int v = __builtin_amdgcn_cvt_pk_fp8_f32(a, b, 0, false);
    v = __builtin_amdgcn_cvt_pk_fp8_f32(c, d, v, true);
    return (uint)v;
}

__device__ __forceinline__ void gload16(const void* g, void* l) {
    __builtin_amdgcn_global_load_lds(
        (const __attribute__((address_space(1))) unsigned int*)g,
        (__attribute__((address_space(3))) unsigned int*)l, 16, 0, 0);
}

__device__ __forceinline__ double wave_sum(double v) {
#pragma unroll
    for (int s = 32; s > 0; s >>= 1) v += __shfl_down(v, s, 64);
    return v;
}

// k-permutation within each 64-byte k-group: orig chunk c=k>>3 (ks=c>>2,
// quad=c&3) stored at pos quad*16 + ks*8 + (k&7).  One b128 at unit `quad`
// yields ks0 in bytes[0:8) and ks1 in bytes[8:16).
__device__ __forceinline__ int kperm(int kk) {   // kk in [0,64), mult of 4
    int c = kk >> 3;
    return (c & 3) * 16 + (c >> 2) * 8 + (kk & 7);
}

// Partials (doubles): [0,1024) t1 | [1024,2048) kl | [2048,2560) t2
// | [2560,3072) t3.  Every slot written every call (no memset).

// ---------------------------------------------------------------------------
// Merged prep. Blocks [0,4096): K -> Kb (fp8, k-permuted) + KTb (fp8,
// transposed, k-permuted).  Blocks [4096,4608): U -> fT (fp8 [j][k] permuted).
// ---------------------------------------------------------------------------
__global__ __launch_bounds__(256) void k_prep(const float* __restrict__ K,
                                              const float* __restrict__ U,
                                              uchar* __restrict__ Kb,
                                              uchar* __restrict__ KTb,
                                              uchar* __restrict__ fT,
                                              const void* epsp, const void* lamp) {
    __shared__ float tile[64][65];
    const int t = threadIdx.x;
    const int tx = t & 15, ty = t >> 4;
    const int bid = blockIdx.x;
    const int pp = kperm(tx * 4);

    if (bid < 4096) {
        const int c0 = (bid & 63) * 64, r0 = (bid >> 6) * 64;
#pragma unroll
        for (int it = 0; it < 4; ++it) {
            int row = ty + it * 16;
            float4 v = *(const float4*)&K[(size_t)(r0 + row) * NN + c0 + tx * 4];
            *(uint*)&Kb[(size_t)(r0 + row) * NN + c0 + pp] =
                pack4_fp8(v.x, v.y, v.z, v.w);
            tile[row][tx * 4 + 0] = v.x;
            tile[row][tx * 4 + 1] = v.y;
            tile[row][tx * 4 + 2] = v.z;
            tile[row][tx * 4 + 3] = v.w;
        }
        __syncthreads();
#pragma unroll
        for (int it = 0; it < 4; ++it) {
            int row = ty + it * 16;  // col within tile -> KT row (c0+row)
            *(uint*)&KTb[(size_t)(c0 + row) * NN + r0 + pp] =
                pack4_fp8(tile[tx * 4 + 0][row], tile[tx * 4 + 1][row],
                          tile[tx * 4 + 2][row], tile[tx * 4 + 3][row]);
        }
    } else {
        const int r = bid - 4096;
        const int c0 = (r & 7) * 64;   // U col tile (j)
        const int r0 = (r >> 3) * 64;  // U row tile (k)
        const float eps = scal_val(epsp), lam = scal_val(lamp);
        const float rr = lam / eps;
#pragma unroll
        for (int it = 0; it < 4; ++it) {
            int row = ty + it * 16;
            float4 v = *(const float4*)&U[(size_t)(r0 + row) * BB + c0 + tx * 4];
            float uu[4] = {v.x, v.y, v.z, v.w};
#pragma unroll
            for (int k = 0; k < 4; ++k) {
                float L = __logf(lam / (lam - uu[k]));
                tile[row][tx * 4 + k] = __expf(rr * L);
            }
        }
        __syncthreads();
#pragma unroll
        for (int it = 0; it < 4; ++it) {
            int row = ty + it * 16;
            *(uint*)&fT[(size_t)(c0 + row) * NN + r0 + pp] =
                pack4_fp8(tile[tx * 4 + 0][row], tile[tx * 4 + 1][row],
                          tile[tx * 4 + 2][row], tile[tx * 4 + 3][row]);
        }
    }
}

// ---------------------------------------------------------------------------
// GEMM1 (fp8 MFMA, K-split 4): partial Y1 = Kb@f over K-quarter, stored bf16.
// Tile 128(M)x64(j), BK=64, dbuf, permuted-b128 LDS.  Grid 1024 (4/CU).
// ---------------------------------------------------------------------------
__global__ __launch_bounds__(256) void k_gemm1(const uchar* __restrict__ Kb,
                                               const uchar* __restrict__ fT,
                                               ushort* __restrict__ Y1b) {
    __shared__ __align__(16) uchar As[2][128 * 64];   // 16 KB
    __shared__ __align__(16) uchar Bf[2][64 * 64];    //  8 KB

    const int tid = threadIdx.x;
    const int lane = tid & 63;
    const int w = tid >> 6;
    const int wm = w & 1, wn = w >> 1;
    const int bid = blockIdx.x;
    const int kh = bid & 3;                  // K-quarter
    const int i0 = ((bid >> 2) & 31) * 128;  // M panel
    const int j0 = (bid >> 7) * 64;          // j panel
    const int quad = lane >> 4;
    const int l15 = lane & 15;
    const int sw = (l15 >> 1) & 3;           // read-side unit swizzle key

    f32x4 zero = {0.f, 0.f, 0.f, 0.f};
    f32x4 acc[4][2];
#pragma unroll
    for (int mt = 0; mt < 4; ++mt)
#pragma unroll
        for (int nt = 0; nt < 2; ++nt) acc[mt][nt] = zero;

    const int rl = lane >> 2;                              // 0..15 row in slab
    const int goff = ((lane & 3) ^ ((lane >> 3) & 3)) * 16; // swizzled unit

    auto stage = [&](int k0, int b) {
#pragma unroll
        for (int it = 0; it < 2; ++it) {
            const int rbase = w * 32 + it * 16;
            gload16(Kb + (size_t)(i0 + rbase + rl) * NN + k0 + goff,
                    &As[b][rbase * 64]);
        }
        gload16(fT + (size_t)(j0 + w * 16 + rl) * NN + k0 + goff,
                &Bf[b][(w * 16) * 64]);
    };

    const int kbase = kh * (NN / 4);
    stage(kbase, 0);
    __syncthreads();
    const int uoff = ((quad ^ sw) << 4);
    for (int step = 0; step < NN / 256; ++step) {   // 16 steps of BK=64
        const int cur = step & 1;
        if (step < NN / 256 - 1) stage(kbase + (step + 1) * 64, cur ^ 1);
        long2v av[4], bv[2];
#pragma unroll
        for (int mt = 0; mt < 4; ++mt)
            av[mt] = *(const long2v*)&As[cur][(wm * 64 + mt * 16 + l15) * 64 + uoff];
#pragma unroll
        for (int nt = 0; nt < 2; ++nt)
            bv[nt] = *(const long2v*)&Bf[cur][(wn * 32 + nt * 16 + l15) * 64 + uoff];
#pragma unroll
        for (int mt = 0; mt < 4; ++mt)
#pragma unroll
            for (int nt = 0; nt < 2; ++nt) {
                acc[mt][nt] = __builtin_amdgcn_mfma_f32_16x16x32_fp8_fp8(
                    av[mt].x, bv[nt].x, acc[mt][nt], 0, 0, 0);
                acc[mt][nt] = __builtin_amdgcn_mfma_f32_16x16x32_fp8_fp8(
                    av[mt].y, bv[nt].y, acc[mt][nt], 0, 0, 0);
            }
        __syncthreads();
    }

    // Store bf16 partial [kh][i][j].  C/D layout: col=lane&15, row=quad*4+reg.
    ushort* o1 = Y1b + (size_t)kh * NN * BB;
#pragma unroll
    for (int mt = 0; mt < 4; ++mt)
#pragma unroll
        for (int nt = 0; nt < 2; ++nt) {
            const int ib = i0 + wm * 64 + mt * 16 + quad * 4;
            const int j = j0 + wn * 32 + nt * 16 + l15;
#pragma unroll
            for (int r = 0; r < 4; ++r)
                o1[(size_t)(ib + r) * BB + j] = f2bf(acc[mt][nt][r]);
        }
}

// ---------------------------------------------------------------------------
// Epilogue: Y1 = sum of 4 bf16 quarters; a = P/Y1; t2 += P*log(a), t3 += P;
// aT (fp8 * 2^14, [j][i] k-permuted) via LDS transpose.  No atomics.
// ---------------------------------------------------------------------------
__global__ __launch_bounds__(256) void k_epi(const ushort* __restrict__ Y1b,
                                             const float* __restrict__ P,
                                             uchar* __restrict__ aT,
                                             double* __restrict__ parts) {
    __shared__ float ta[64][65];
    __shared__ double bred[4][2];
    const int t = threadIdx.x;
    const int lane = t & 63;
    const int w = t >> 6;
    const int tx = t & 15, ty = t >> 4;
    const int j0 = blockIdx.x * 64;
    const int i0 = blockIdx.y * 64;
    const int bid = blockIdx.y * 8 + blockIdx.x;
    const size_t H = (size_t)NN * BB;
    const int pp = kperm(tx * 4);

    double t2 = 0.0, t3 = 0.0;
#pragma unroll
    for (int it = 0; it < 4; ++it) {
        int row = ty + it * 16;
        size_t off = (size_t)(i0 + row) * BB + j0 + tx * 4;
        ushort4v q0 = *(const ushort4v*)(Y1b + off);
        ushort4v q1 = *(const ushort4v*)(Y1b + H + off);
        ushort4v q2 = *(const ushort4v*)(Y1b + 2 * H + off);
        ushort4v q3 = *(const ushort4v*)(Y1b + 3 * H + off);
        float4 p4 = *(const float4*)(P + off);
        float pv[4] = {p4.x, p4.y, p4.z, p4.w};
#pragma unroll
        for (int e = 0; e < 4; ++e) {
            float y1 = bf2f(q0[e]) + bf2f(q1[e]) + bf2f(q2[e]) + bf2f(q3[e]);
            float aij = pv[e] / y1;
            t2 += (double)(pv[e] * __logf(aij));
            t3 += (double)pv[e];
            ta[row][tx * 4 + e] = aij * ASCALE;
        }
    }
    __syncthreads();
#pragma unroll
    for (int it = 0; it < 4; ++it) {
        int row = ty + it * 16;  // col within tile -> aT row (j0+row)
        *(uint*)&aT[(size_t)(j0 + row) * NN + i0 + pp] =
            pack4_fp8(ta[tx * 4 + 0][row], ta[tx * 4 + 1][row],
                      ta[tx * 4 + 2][row], ta[tx * 4 + 3][row]);
    }

    t2 = wave_sum(t2); t3 = wave_sum(t3);
    if (lane == 0) { bred[w][0] = t2; bred[w][1] = t3; }
    __syncthreads();
    if (t == 0) {
        double b = 0, c = 0;
#pragma unroll
        for (int ww = 0; ww < 4; ++ww) { b += bred[ww][0]; c += bred[ww][1]; }
        parts[2048 + bid] = b;
        parts[2560 + bid] = c;
    }
}

// ---------------------------------------------------------------------------
// GEMM2 (fp8 MFMA, K-split 4): partial S' = KTb @ a' (a scaled 2^14).
// Epilogue (both linear in S): t1 += g*S, kl -= f*(1+L)*S, with
// f,L,g=f*rr*L recomputed from U.  Grid 1024, no atomics.
// ---------------------------------------------------------------------------
__global__ __launch_bounds__(256) void k_gemm2(const uchar* __restrict__ KTb,
                                               const uchar* __restrict__ aT,
                                               const float* __restrict__ U,
                                               const void* epsp, const void* lamp,
                                               double* __restrict__ parts) {
    __shared__ __align__(16) uchar As[2][128 * 64];
    __shared__ __align__(16) uchar Bs[2][64 * 64];
    __shared__ double bred[4][2];

    const float eps = scal_val(epsp), lam = scal_val(lamp);
    const float rr = lam / eps;
    const int tid = threadIdx.x;
    const int lane = tid & 63;
    const int w = tid >> 6;
    const int wm = w & 1, wn = w >> 1;
    const int bid = blockIdx.x;
    const int kh = bid & 3;
    const int i0 = ((bid >> 2) & 31) * 128;
    const int j0 = (bid >> 7) * 64;
    const int quad = lane >> 4;
    const int l15 = lane & 15;
    const int sw = (l15 >> 1) & 3;

    f32x4 zero = {0.f, 0.f, 0.f, 0.f};
    f32x4 acc[4][2];
#pragma unroll
    for (int mt = 0; mt < 4; ++mt)
#pragma unroll
        for (int nt = 0; nt < 2; ++nt) acc[mt][nt] = zero;

    const int rl = lane >> 2;
    const int goff = ((lane & 3) ^ ((lane >> 3) & 3)) * 16;

    auto stage = [&](int k0, int b) {
#pragma unroll
        for (int it = 0; it < 2; ++it) {
            const int rbase = w * 32 + it * 16;
            gload16(KTb + (size_t)(i0 + rbase + rl) * NN + k0 + goff,
                    &As[b][rbase * 64]);
        }
        gload16(aT + (size_t)(j0 + w * 16 + rl) * NN + k0 + goff,
                &Bs[b][(w * 16) * 64]);
    };

    const int kbase = kh * (NN / 4);
    stage(kbase, 0);
    __syncthreads();
    const int uoff = ((quad ^ sw) << 4);
    for (int step = 0; step < NN / 256; ++step) {
        const int cur = step & 1;
        if (step < NN / 256 - 1) stage(kbase + (step + 1) * 64, cur ^ 1);
        long2v av[4], bv[2];
#pragma unroll
        for (int mt = 0; mt < 4; ++mt)
            av[mt] = *(const long2v*)&As[cur][(wm * 64 + mt * 16 + l15) * 64 + uoff];
#pragma unroll
        for (int nt = 0; nt < 2; ++nt)
            bv[nt] = *(const long2v*)&Bs[cur][(wn * 32 + nt * 16 + l15) * 64 + uoff];
#pragma unroll
        for (int mt = 0; mt < 4; ++mt)
#pragma unroll
            for (int nt = 0; nt < 2; ++nt) {
                acc[mt][nt] = __builtin_amdgcn_mfma_f32_16x16x32_fp8_fp8(
                    av[mt].x, bv[nt].x, acc[mt][nt], 0, 0, 0);
                acc[mt][nt] = __builtin_amdgcn_mfma_f32_16x16x32_fp8_fp8(
                    av[mt].y, bv[nt].y, acc[mt][nt], 0, 0, 0);
            }
        __syncthreads();
    }

    double t1p = 0.0, klp = 0.0;
#pragma unroll
    for (int mt = 0; mt < 4; ++mt)
#pragma unroll
        for (int nt = 0; nt < 2; ++nt) {
            const int ib = i0 + wm * 64 + mt * 16 + quad * 4;  // k index
            const int j = j0 + wn * 32 + nt * 16 + l15;
#pragma unroll
            for (int r = 0; r < 4; ++r) {
                float s = acc[mt][nt][r] * AINV;
                float u = U[(size_t)(ib + r) * BB + j];
                float L = __logf(lam / (lam - u));
                float fv = __expf(rr * L);
                t1p += (double)(fv * rr * L * s);       // g*S
                klp -= (double)(fv * (1.0f + L) * s);   // -f*(1+L)*S
            }
        }

    t1p = wave_sum(t1p); klp = wave_sum(klp);
    if (lane == 0) { bred[w][0] = t1p; bred[w][1] = klp; }
    __syncthreads();
    if (tid == 0) {
        double a = 0, b = 0;
#pragma unroll
        for (int ww = 0; ww < 4; ++ww) { a += bred[ww][0]; b += bred[ww][1]; }
        parts[bid] = a;
        parts[1024 + bid] = b;
    }
}

// ---------------------------------------------------------------------------
// Final: sum partials, out = eps*(t1+t2-t3) + lam*kl
// ---------------------------------------------------------------------------
__global__ __launch_bounds__(256) void k_final(const double* __restrict__ parts,
                                               const void* epsp, const void* lamp,
                                               float* __restrict__ out) {
    __shared__ double red[4][4];
    const int tid = threadIdx.x;
    const int lane = tid & 63, w = tid >> 6;
    double s0 = 0.0, s1 = 0.0, s2 = 0.0, s3 = 0.0;
    for (int i = tid; i < 1024; i += 256) {
        s0 += parts[i];          // t1
        s1 += parts[1024 + i];   // kl
    }
    for (int i = tid; i < 512; i += 256) {
        s2 += parts[2048 + i];   // t2
        s3 += parts[2560 + i];   // t3
    }
    s0 = wave_sum(s0); s1 = wave_sum(s1); s2 = wave_sum(s2); s3 = wave_sum(s3);
    if (lane == 0) { red[w][0] = s0; red[w][1] = s1; red[w][2] = s2; red[w][3] = s3; }
    __syncthreads();
    if (tid == 0) {
        double t1 = 0, kl = 0, t2 = 0, t3 = 0;
#pragma unroll
        for (int ww = 0; ww < 4; ++ww) {
            t1 += red[ww][0]; kl += red[ww][1]; t2 += red[ww][2]; t3 += red[ww][3];
        }
        float eps = scal_val(epsp), lam = scal_val(lamp);
        out[0] = (float)((double)eps * (t1 + t2 - t3) + (double)lam * kl);
    }
}

extern "C" void kernel_launch(void* const* d_in, const int* in_sizes, int n_in,
                              void* d_out, int out_size, void* d_ws, size_t ws_size,
                              hipStream_t stream) {
    const float* U = (const float*)d_in[0];
    const float* P = (const float*)d_in[1];
    const float* K = (const float*)d_in[2];
    const void* epsp = d_in[3];
    const void* lamp = d_in[4];

    // ws: parts 24KB (pad 64KB) | Kb 16M | KTb 16M | fT 2M | aT 2M | Y1b 16M
    double* parts = (double*)d_ws;
    char* base = (char*)d_ws + (64 << 10);
    uchar* Kb   = (uchar*)base;
    uchar* KTb  = (uchar*)(base + ((size_t)16 << 20));
    uchar* fT   = (uchar*)(base + ((size_t)32 << 20));
    uchar* aT   = (uchar*)(base + ((size_t)34 << 20));
    ushort* Y1b = (ushort*)(base + ((size_t)36 << 20));

    k_prep<<<4608, 256, 0, stream>>>(K, U, Kb, KTb, fT, epsp, lamp);
    k_gemm1<<<1024, 256, 0, stream>>>(Kb, fT, Y1b);
    k_epi<<<dim3(8, 64), 256, 0, stream>>>(Y1b, P, aT, parts);
    k_gemm2<<<1024, 256, 0, stream>>>(KTb, aT, U, epsp, lamp, parts);
    k_final<<<1, 256, 0, stream>>>(parts, epsp, lamp, (float*)d_out);
}

// Round 10
// 164.598 us; speedup vs baseline: 1.1585x; 1.0272x over previous
//
#include <hip/hip_runtime.h>

#define NN 4096
#define BB 512

typedef __attribute__((ext_vector_type(4))) float f32x4;    // MFMA C/D frag
typedef __attribute__((ext_vector_type(2))) long long2v;    // 16B LDS read
typedef unsigned short ushort;
typedef unsigned char uchar;
typedef unsigned int uint;
typedef __attribute__((ext_vector_type(4))) ushort ushort4v;

#define ASCALE 16384.0f            // 2^14 scale for a -> fp8
#define AINV   6.103515625e-05f    // 2^-14

__device__ __forceinline__ float scal_val(const void* p) {
    int b = *(const int*)p;
    if (b >= 1 && b <= 1000000) return (float)b;
    return __int_as_float(b);
}

// f32 -> bf16 bits (RNE) and back
__device__ __forceinline__ ushort f2bf(float x) {
    unsigned u = __float_as_uint(x);
    u += 0x7fffu + ((u >> 16) & 1u);
    return (ushort)(u >> 16);
}
__device__ __forceinline__ float bf2f(ushort b) {
    return __uint_as_float((uint)b << 16);
}

// pack 4 floats -> 4 fp8 e4m3 bytes (OCP, RNE+sat via v_cvt_pk_fp8_f32)
__device__ __forceinline__ uint pack4_fp8(float a, float b, float c, float d) {
    int v = __builtin_amdgcn_cvt_pk_fp8_f32(a, b, 0, false);
    v = __builtin_amdgcn_cvt_pk_fp8_f32(c, d, v, true);
    return (uint)v;
}

__device__ __forceinline__ void gload16(const void* g, void* l) {
    __builtin_amdgcn_global_load_lds(
        (const __attribute__((address_space(1))) unsigned int*)g,
        (__attribute__((address_space(3))) unsigned int*)l, 16, 0, 0);
}

__device__ __forceinline__ double wave_sum(double v) {
#pragma unroll
    for (int s = 32; s > 0; s >>= 1) v += __shfl_down(v, s, 64);
    return v;
}

// k-permutation within each 64-byte k-group: orig chunk c=k>>3 (ks=c>>2,
// quad=c&3) stored at pos quad*16 + ks*8 + (k&7).  One b128 at unit `quad`
// yields ks0 in bytes[0:8) and ks1 in bytes[8:16).
__device__ __forceinline__ int kperm(int kk) {   // kk in [0,64), mult of 4
    int c = kk >> 3;
    return (c & 3) * 16 + (c >> 2) * 8 + (kk & 7);
}
// in-row byte position with the ds-bank XOR swizzle baked in (key from the
// TILE-LOCAL row; r0/c0/j0 are multiples of 64 so (row>>1)&3 is invariant)
__device__ __forceinline__ int bpos(int row, int pp) {   // pp = kperm(k&63)
    return (((pp >> 4) ^ ((row >> 1) & 3)) << 4) | (pp & 15);
}

// Blocked global layouts (tile = the exact LDS image of one K-step):
//   Kb/KTb : tile 128 rows x 64 B; off = ((i>>7)*64 + (k>>6))*8192 + (i&127)*64 + bpos
//   fT/aT  : tile  64 rows x 64 B; off = ((j>>6)*64 + (k>>6))*4096 + (j&63)*64 + bpos
// => one K-step's A-tile is 8 KB contiguous, B-tile 4 KB contiguous; staging
//    is a pure linear copy (lane L -> bytes [L*16, L*16+16)).

// Partials (doubles): [0,1024) t1 | [1024,2048) kl | [2048,2560) t2
// | [2560,3072) t3.  Every slot written every call (no memset).

// ---------------------------------------------------------------------------
// Merged prep. Blocks [0,4096): K -> Kb + KTb (fp8, blocked+swizzled).
// Blocks [4096,4608): U -> fT (fp8 [j][k], blocked+swizzled).
// ---------------------------------------------------------------------------
__global__ __launch_bounds__(256) void k_prep(const float* __restrict__ K,
                                              const float* __restrict__ U,
                                              uchar* __restrict__ Kb,
                                              uchar* __restrict__ KTb,
                                              uchar* __restrict__ fT,
                                              const void* epsp, const void* lamp) {
    __shared__ float tile[64][65];
    const int t = threadIdx.x;
    const int tx = t & 15, ty = t >> 4;
    const int bid = blockIdx.x;
    const int pp = kperm(tx * 4);

    if (bid < 4096) {
        const int c0 = (bid & 63) * 64, r0 = (bid >> 6) * 64;
#pragma unroll
        for (int it = 0; it < 4; ++it) {
            int row = ty + it * 16;
            float4 v = *(const float4*)&K[(size_t)(r0 + row) * NN + c0 + tx * 4];
            int i = r0 + row;
            int off = (((i >> 7) * 64 + (c0 >> 6)) << 13) + (i & 127) * 64 +
                      bpos(row, pp);
            *(uint*)&Kb[off] = pack4_fp8(v.x, v.y, v.z, v.w);
            tile[row][tx * 4 + 0] = v.x;
            tile[row][tx * 4 + 1] = v.y;
            tile[row][tx * 4 + 2] = v.z;
            tile[row][tx * 4 + 3] = v.w;
        }
        __syncthreads();
#pragma unroll
        for (int it = 0; it < 4; ++it) {
            int row = ty + it * 16;  // col within tile -> KT row (c0+row)
            int i = c0 + row;
            int off = (((i >> 7) * 64 + (r0 >> 6)) << 13) + (i & 127) * 64 +
                      bpos(row, pp);
            *(uint*)&KTb[off] =
                pack4_fp8(tile[tx * 4 + 0][row], tile[tx * 4 + 1][row],
                          tile[tx * 4 + 2][row], tile[tx * 4 + 3][row]);
        }
    } else {
        const int r = bid - 4096;
        const int c0 = (r & 7) * 64;   // U col tile (j)
        const int r0 = (r >> 3) * 64;  // U row tile (k)
        const float eps = scal_val(epsp), lam = scal_val(lamp);
        const float rr = lam / eps;
#pragma unroll
        for (int it = 0; it < 4; ++it) {
            int row = ty + it * 16;
            float4 v = *(const float4*)&U[(size_t)(r0 + row) * BB + c0 + tx * 4];
            float uu[4] = {v.x, v.y, v.z, v.w};
#pragma unroll
            for (int k = 0; k < 4; ++k) {
                float L = __logf(lam / (lam - uu[k]));
                tile[row][tx * 4 + k] = __expf(rr * L);
            }
        }
        __syncthreads();
#pragma unroll
        for (int it = 0; it < 4; ++it) {
            int row = ty + it * 16;  // j-local row (j = c0+row)
            int j = c0 + row;
            int off = (((j >> 6) * 64 + (r0 >> 6)) << 12) + (j & 63) * 64 +
                      bpos(row, pp);
            *(uint*)&fT[off] =
                pack4_fp8(tile[tx * 4 + 0][row], tile[tx * 4 + 1][row],
                          tile[tx * 4 + 2][row], tile[tx * 4 + 3][row]);
        }
    }
}

// ---------------------------------------------------------------------------
// GEMM1 (fp8 MFMA, K-split 4): partial Y1 = Kb@f over K-quarter, stored bf16.
// Tile 128(M)x64(j), BK=64, dbuf.  Staging = linear contiguous copies from
// the blocked layout.  Grid 1024 (4/CU).
// ---------------------------------------------------------------------------
__global__ __launch_bounds__(256) void k_gemm1(const uchar* __restrict__ Kb,
                                               const uchar* __restrict__ fT,
                                               ushort* __restrict__ Y1b) {
    __shared__ __align__(16) uchar As[2][128 * 64];   // 16 KB
    __shared__ __align__(16) uchar Bf[2][64 * 64];    //  8 KB

    const int tid = threadIdx.x;
    const int lane = tid & 63;
    const int w = tid >> 6;
    const int wm = w & 1, wn = w >> 1;
    const int bid = blockIdx.x;
    const int kh = bid & 3;                  // K-quarter
    const int i0 = ((bid >> 2) & 31) * 128;  // M panel
    const int j0 = (bid >> 7) * 64;          // j panel
    const int quad = lane >> 4;
    const int l15 = lane & 15;
    const int sw = (l15 >> 1) & 3;           // read-side unit swizzle key

    f32x4 zero = {0.f, 0.f, 0.f, 0.f};
    f32x4 acc[4][2];
#pragma unroll
    for (int mt = 0; mt < 4; ++mt)
#pragma unroll
        for (int nt = 0; nt < 2; ++nt) acc[mt][nt] = zero;

    const uchar* apanel = Kb + ((size_t)(i0 >> 7) << 19);  // *64*8192
    const uchar* bpanel = fT + ((size_t)(j0 >> 6) << 18);  // *64*4096

    auto stage = [&](int ks, int b) {
        const uchar* ga = apanel + ((size_t)ks << 13) + w * 2048 + lane * 16;
        gload16(ga, &As[b][w * 2048]);
        gload16(ga + 1024, &As[b][w * 2048 + 1024]);
        const uchar* gb = bpanel + ((size_t)ks << 12) + w * 1024 + lane * 16;
        gload16(gb, &Bf[b][w * 1024]);
    };

    const int ks0 = kh * 16;
    stage(ks0, 0);
    __syncthreads();
    const int uoff = ((quad ^ sw) << 4);
    for (int step = 0; step < 16; ++step) {   // 16 steps of BK=64
        const int cur = step & 1;
        if (step < 15) stage(ks0 + step + 1, cur ^ 1);
        long2v av[4], bv[2];
#pragma unroll
        for (int mt = 0; mt < 4; ++mt)
            av[mt] = *(const long2v*)&As[cur][(wm * 64 + mt * 16 + l15) * 64 + uoff];
#pragma unroll
        for (int nt = 0; nt < 2; ++nt)
            bv[nt] = *(const long2v*)&Bf[cur][(wn * 32 + nt * 16 + l15) * 64 + uoff];
#pragma unroll
        for (int mt = 0; mt < 4; ++mt)
#pragma unroll
            for (int nt = 0; nt < 2; ++nt) {
                acc[mt][nt] = __builtin_amdgcn_mfma_f32_16x16x32_fp8_fp8(
                    av[mt].x, bv[nt].x, acc[mt][nt], 0, 0, 0);
                acc[mt][nt] = __builtin_amdgcn_mfma_f32_16x16x32_fp8_fp8(
                    av[mt].y, bv[nt].y, acc[mt][nt], 0, 0, 0);
            }
        __syncthreads();
    }

    // Store bf16 partial [kh][i][j].  C/D layout: col=lane&15, row=quad*4+reg.
    ushort* o1 = Y1b + (size_t)kh * NN * BB;
#pragma unroll
    for (int mt = 0; mt < 4; ++mt)
#pragma unroll
        for (int nt = 0; nt < 2; ++nt) {
            const int ib = i0 + wm * 64 + mt * 16 + quad * 4;
            const int j = j0 + wn * 32 + nt * 16 + l15;
#pragma unroll
            for (int r = 0; r < 4; ++r)
                o1[(size_t)(ib + r) * BB + j] = f2bf(acc[mt][nt][r]);
        }
}

// ---------------------------------------------------------------------------
// Epilogue: Y1 = sum of 4 bf16 quarters; a = P/Y1; t2 += P*log(a), t3 += P;
// aT (fp8 * 2^14, blocked+swizzled) via LDS transpose.  No atomics.
// ---------------------------------------------------------------------------
__global__ __launch_bounds__(256) void k_epi(const ushort* __restrict__ Y1b,
                                             const float* __restrict__ P,
                                             uchar* __restrict__ aT,
                                             double* __restrict__ parts) {
    __shared__ float ta[64][65];
    __shared__ double bred[4][2];
    const int t = threadIdx.x;
    const int lane = t & 63;
    const int w = t >> 6;
    const int tx = t & 15, ty = t >> 4;
    const int j0 = blockIdx.x * 64;
    const int i0 = blockIdx.y * 64;
    const int bid = blockIdx.y * 8 + blockIdx.x;
    const size_t H = (size_t)NN * BB;
    const int pp = kperm(tx * 4);

    double t2 = 0.0, t3 = 0.0;
#pragma unroll
    for (int it = 0; it < 4; ++it) {
        int row = ty + it * 16;
        size_t off = (size_t)(i0 + row) * BB + j0 + tx * 4;
        ushort4v q0 = *(const ushort4v*)(Y1b + off);
        ushort4v q1 = *(const ushort4v*)(Y1b + H + off);
        ushort4v q2 = *(const ushort4v*)(Y1b + 2 * H + off);
        ushort4v q3 = *(const ushort4v*)(Y1b + 3 * H + off);
        float4 p4 = *(const float4*)(P + off);
        float pv[4] = {p4.x, p4.y, p4.z, p4.w};
#pragma unroll
        for (int e = 0; e < 4; ++e) {
            float y1 = bf2f(q0[e]) + bf2f(q1[e]) + bf2f(q2[e]) + bf2f(q3[e]);
            float aij = pv[e] / y1;
            t2 += (double)(pv[e] * __logf(aij));
            t3 += (double)pv[e];
            ta[row][tx * 4 + e] = aij * ASCALE;
        }
    }
    __syncthreads();
#pragma unroll
    for (int it = 0; it < 4; ++it) {
        int row = ty + it * 16;  // col within tile -> aT row (j0+row), k=i0+tx*4
        int j = j0 + row;
        int off = (((j >> 6) * 64 + (i0 >> 6)) << 12) + (j & 63) * 64 +
                  bpos(row, pp);
        *(uint*)&aT[off] =
            pack4_fp8(ta[tx * 4 + 0][row], ta[tx * 4 + 1][row],
                      ta[tx * 4 + 2][row], ta[tx * 4 + 3][row]);
    }

    t2 = wave_sum(t2); t3 = wave_sum(t3);
    if (lane == 0) { bred[w][0] = t2; bred[w][1] = t3; }
    __syncthreads();
    if (t == 0) {
        double b = 0, c = 0;
#pragma unroll
        for (int ww = 0; ww < 4; ++ww) { b += bred[ww][0]; c += bred[ww][1]; }
        parts[2048 + bid] = b;
        parts[2560 + bid] = c;
    }
}

// ---------------------------------------------------------------------------
// GEMM2 (fp8 MFMA, K-split 4): partial S' = KTb @ a' (a scaled 2^14).
// Epilogue (both linear in S): t1 += g*S, kl -= f*(1+L)*S.  Grid 1024.
// ---------------------------------------------------------------------------
__global__ __launch_bounds__(256) void k_gemm2(const uchar* __restrict__ KTb,
                                               const uchar* __restrict__ aT,
                                               const float* __restrict__ U,
                                               const void* epsp, const void* lamp,
                                               double* __restrict__ parts) {
    __shared__ __align__(16) uchar As[2][128 * 64];
    __shared__ __align__(16) uchar Bs[2][64 * 64];
    __shared__ double bred[4][2];

    const float eps = scal_val(epsp), lam = scal_val(lamp);
    const float rr = lam / eps;
    const int tid = threadIdx.x;
    const int lane = tid & 63;
    const int w = tid >> 6;
    const int wm = w & 1, wn = w >> 1;
    const int bid = blockIdx.x;
    const int kh = bid & 3;
    const int i0 = ((bid >> 2) & 31) * 128;
    const int j0 = (bid >> 7) * 64;
    const int quad = lane >> 4;
    const int l15 = lane & 15;
    const int sw = (l15 >> 1) & 3;

    f32x4 zero = {0.f, 0.f, 0.f, 0.f};
    f32x4 acc[4][2];
#pragma unroll
    for (int mt = 0; mt < 4; ++mt)
#pragma unroll
        for (int nt = 0; nt < 2; ++nt) acc[mt][nt] = zero;

    const uchar* apanel = KTb + ((size_t)(i0 >> 7) << 19);
    const uchar* bpanel = aT + ((size_t)(j0 >> 6) << 18);

    auto stage = [&](int ks, int b) {
        const uchar* ga = apanel + ((size_t)ks << 13) + w * 2048 + lane * 16;
        gload16(ga, &As[b][w * 2048]);
        gload16(ga + 1024, &As[b][w * 2048 + 1024]);
        const uchar* gb = bpanel + ((size_t)ks << 12) + w * 1024 + lane * 16;
        gload16(gb, &Bs[b][w * 1024]);
    };

    const int ks0 = kh * 16;
    stage(ks0, 0);
    __syncthreads();
    const int uoff = ((quad ^ sw) << 4);
    for (int step = 0; step < 16; ++step) {
        const int cur = step & 1;
        if (step < 15) stage(ks0 + step + 1, cur ^ 1);
        long2v av[4], bv[2];
#pragma unroll
        for (int mt = 0; mt < 4; ++mt)
            av[mt] = *(const long2v*)&As[cur][(wm * 64 + mt * 16 + l15) * 64 + uoff];
#pragma unroll
        for (int nt = 0; nt < 2; ++nt)
            bv[nt] = *(const long2v*)&Bs[cur][(wn * 32 + nt * 16 + l15) * 64 + uoff];
#pragma unroll
        for (int mt = 0; mt < 4; ++mt)
#pragma unroll
            for (int nt = 0; nt < 2; ++nt) {
                acc[mt][nt] = __builtin_amdgcn_mfma_f32_16x16x32_fp8_fp8(
                    av[mt].x, bv[nt].x, acc[mt][nt], 0, 0, 0);
                acc[mt][nt] = __builtin_amdgcn_mfma_f32_16x16x32_fp8_fp8(
                    av[mt].y, bv[nt].y, acc[mt][nt], 0, 0, 0);
            }
        __syncthreads();
    }

    double t1p = 0.0, klp = 0.0;
#pragma unroll
    for (int mt = 0; mt < 4; ++mt)
#pragma unroll
        for (int nt = 0; nt < 2; ++nt) {
            const int ib = i0 + wm * 64 + mt * 16 + quad * 4;  // k index
            const int j = j0 + wn * 32 + nt * 16 + l15;
#pragma unroll
            for (int r = 0; r < 4; ++r) {
                float s = acc[mt][nt][r] * AINV;
                float u = U[(size_t)(ib + r) * BB + j];
                float L = __logf(lam / (lam - u));
                float fv = __expf(rr * L);
                t1p += (double)(fv * rr * L * s);       // g*S
                klp -= (double)(fv * (1.0f + L) * s);   // -f*(1+L)*S
            }
        }

    t1p = wave_sum(t1p); klp = wave_sum(klp);
    if (lane == 0) { bred[w][0] = t1p; bred[w][1] = klp; }
    __syncthreads();
    if (tid == 0) {
        double a = 0, b = 0;
#pragma unroll
        for (int ww = 0; ww < 4; ++ww) { a += bred[ww][0]; b += bred[ww][1]; }
        parts[bid] = a;
        parts[1024 + bid] = b;
    }
}

// ---------------------------------------------------------------------------
// Final: sum partials, out = eps*(t1+t2-t3) + lam*kl
// ---------------------------------------------------------------------------
__global__ __launch_bounds__(256) void k_final(const double* __restrict__ parts,
                                               const void* epsp, const void* lamp,
                                               float* __restrict__ out) {
    __shared__ double red[4][4];
    const int tid = threadIdx.x;
    const int lane = tid & 63, w = tid >> 6;
    double s0 = 0.0, s1 = 0.0, s2 = 0.0, s3 = 0.0;
    for (int i = tid; i < 1024; i += 256) {
        s0 += parts[i];          // t1
        s1 += parts[1024 + i];   // kl
    }
    for (int i = tid; i < 512; i += 256) {
        s2 += parts[2048 + i];   // t2
        s3 += parts[2560 + i];   // t3
    }
    s0 = wave_sum(s0); s1 = wave_sum(s1); s2 = wave_sum(s2); s3 = wave_sum(s3);
    if (lane == 0) { red[w][0] = s0; red[w][1] = s1; red[w][2] = s2; red[w][3] = s3; }
    __syncthreads();
    if (tid == 0) {
        double t1 = 0, kl = 0, t2 = 0, t3 = 0;
#pragma unroll
        for (int ww = 0; ww < 4; ++ww) {
            t1 += red[ww][0]; kl += red[ww][1]; t2 += red[ww][2]; t3 += red[ww][3];
        }
        float eps = scal_val(epsp), lam = scal_val(lamp);
        out[0] = (float)((double)eps * (t1 + t2 - t3) + (double)lam * kl);
    }
}

extern "C" void kernel_launch(void* const* d_in, const int* in_sizes, int n_in,
                              void* d_out, int out_size, void* d_ws, size_t ws_size,
                              hipStream_t stream) {
    const float* U = (const float*)d_in[0];
    const float* P = (const float*)d_in[1];
    const float* K = (const float*)d_in[2];
    const void* epsp = d_in[3];
    const void* lamp = d_in[4];

    // ws: parts 24KB (pad 64KB) | Kb 16M | KTb 16M | fT 2M | aT 2M | Y1b 16M
    double* parts = (double*)d_ws;
    char* base = (char*)d_ws + (64 << 10);
    uchar* Kb   = (uchar*)base;
    uchar* KTb  = (uchar*)(base + ((size_t)16 << 20));
    uchar* fT   = (uchar*)(base + ((size_t)32 << 20));
    uchar* aT   = (uchar*)(base + ((size_t)34 << 20));
    ushort* Y1b = (ushort*)(base + ((size_t)36 << 20));

    k_prep<<<4608, 256, 0, stream>>>(K, U, Kb, KTb, fT, epsp, lamp);
    k_gemm1<<<1024, 256, 0, stream>>>(Kb, fT, Y1b);
    k_epi<<<dim3(8, 64), 256, 0, stream>>>(Y1b, P, aT, parts);
    k_gemm2<<<1024, 256, 0, stream>>>(KTb, aT, U, epsp, lamp, parts);
    k_final<<<1, 256, 0, stream>>>(parts, epsp, lamp, (float*)d_out);
}